// Round 25
// baseline (87.697 us; speedup 1.0000x reference)
//
#include <hip/hip_runtime.h>
#include <hip/hip_bf16.h>

// ---------------------------------------------------------------------------
// Fused MLP+LSTM for B=131072 rows, v18: chain-split into 3 kernels.
// Diagnosis (24 rounds): the fused per-wave 9-layer serial chain is pinned at
// ~61.4us by latency x the 64-rows/SIMD register cap; no pipe >25% busy.
// Fix: break inter-layer dependencies at kernel boundaries. Intermediates
// h1/h3 stored in FRAGMENT layout in d_ws (lane-local bf16x8, coalesced,
// bit-identical operand round-trip, L3-resident at 33.5MB each).
//   K1 prep  : fp32->bf16 weight frags + bias folding (v12-verified)
//   K2 L1    : x[256]->h1[128]     (FC1 in 64KB LDS, x pair-streamed)
//   K3 L1A+B : h1(+w)->h3[128]     (FC1A_H/FC1A_W/FC1B in 80KB LDS)
//   K4 tail  : h3->out             (FC1C/FC2/FC3/WIH/WHH/FC4 in 56KB LDS)
// Each kernel has no long in-wave chain -> TLP fully hides latency.
// Fallback: if ws_size < ~67MB, run the proven v12 fused kernel (61.4us).
// Operand-swapped MFMA: D = W*act^T keeps batch row at lane&15 throughout.
// ---------------------------------------------------------------------------

typedef __bf16 bf16x8 __attribute__((ext_vector_type(8)));
typedef float  f32x4  __attribute__((ext_vector_type(4)));
typedef int    i32x4  __attribute__((ext_vector_type(4)));

#define MFMA16(A, B, C) __builtin_amdgcn_mfma_f32_16x16x32_bf16((A), (B), (C), 0, 0, 0)

// ws fragment offsets (bf16 elems) — v12 prep layout (verified)
#define WOFF_FC1    0
#define WOFF_FC1A_H 32768
#define WOFF_FC1B   49152
#define WOFF_FC1C   65536
#define WOFF_FC1A_W 73728
#define WOFF_FC2    81920
#define WOFF_FC3    83968
#define WOFF_WIH    84992
#define WOFF_WHH    89088
#define WOFF_FC4    93184
#define WTOT        94208
#define BOFF_FC1  0
#define BOFF_FC1A 128
#define BOFF_FC1B 256
#define BOFF_FC1C 384
#define BOFF_FC2  448
#define BOFF_FC3  480
#define BOFF_LSTM 512
#define BOFF_FC4  640
#define BTOT      672

// ws byte layout beyond weights
#define H1_BYTE_OFF 192512ull                    // 256-aligned, after wsw+wsb
#define HACT_BYTES  33554432ull                  // 131072 x 128 x 2B
#define WS_REQUIRED (H1_BYTE_OFF + 2ull * HACT_BYTES)

// ---------------------------------------------------------------------------
// Fragment mapping (verified since v1):
//   rel -> j = rel&7, lane = (rel>>3)&63, fs = rel>>9, s = fs%ns, t = fs/ns,
//   gq = lane>>4, n = 16t + (lane&15),
//   k = perm ? 16*(2s + (j>>2)) + 4*gq + (j&3) : 32*s + 8*gq + j
// ---------------------------------------------------------------------------
__device__ __forceinline__ void conv_frag(int rel, const float* __restrict__ src,
                                          __bf16* __restrict__ dst,
                                          int ns, int Krow, int kbase, int klim, int perm) {
    int j    = rel & 7;
    int lane = (rel >> 3) & 63;
    int fs   = rel >> 9;
    int s    = fs % ns;
    int t    = fs / ns;
    int gq   = lane >> 4;
    int n    = 16 * t + (lane & 15);
    int k    = perm ? (16 * (2 * s + (j >> 2)) + 4 * gq + (j & 3))
                    : (32 * s + 8 * gq + j);
    float v  = (k < klim) ? src[n * Krow + kbase + k] : 0.f;
    dst[rel] = (__bf16)v;
}

// ---------------------------------------------------------------------------
// Prep: full fp32 -> bf16 fragment conversion + bias folding (runs once).
// ---------------------------------------------------------------------------
__global__ void prep_kernel(const float* __restrict__ fc1w,  const float* __restrict__ fc1b,
                            const float* __restrict__ fc1aw, const float* __restrict__ fc1ab,
                            const float* __restrict__ fc1bw, const float* __restrict__ fc1bb,
                            const float* __restrict__ wgame, const float* __restrict__ fc1cw,
                            const float* __restrict__ fc1cb, const float* __restrict__ fc2w,
                            const float* __restrict__ fc2b,  const float* __restrict__ fc3w,
                            const float* __restrict__ fc3b,  const float* __restrict__ wih,
                            const float* __restrict__ whh,   const float* __restrict__ bih,
                            const float* __restrict__ bhh,   const float* __restrict__ fc4w,
                            const float* __restrict__ fc4b,
                            __bf16* __restrict__ wsw, float* __restrict__ wsb) {
    int idx = blockIdx.x * 256 + threadIdx.x;
    if (idx < WTOT) {
        if      (idx < WOFF_FC1A_H) conv_frag(idx - WOFF_FC1,    fc1w,  wsw + WOFF_FC1,    8, 256,   0, 256, 0);
        else if (idx < WOFF_FC1B)   conv_frag(idx - WOFF_FC1A_H, fc1aw, wsw + WOFF_FC1A_H, 4, 164,   0, 128, 1);
        else if (idx < WOFF_FC1C)   conv_frag(idx - WOFF_FC1B,   fc1bw, wsw + WOFF_FC1B,   4, 128,   0, 128, 1);
        else if (idx < WOFF_FC1A_W) conv_frag(idx - WOFF_FC1C,   fc1cw, wsw + WOFF_FC1C,   4, 140,   0, 128, 1);
        else if (idx < WOFF_FC2)    conv_frag(idx - WOFF_FC1A_W, fc1aw, wsw + WOFF_FC1A_W, 2, 164, 128,  36, 0);
        else if (idx < WOFF_FC3)    conv_frag(idx - WOFF_FC2,    fc2w,  wsw + WOFF_FC2,    2,  64,   0,  64, 1);
        else if (idx < WOFF_WIH)    conv_frag(idx - WOFF_FC3,    fc3w,  wsw + WOFF_FC3,    1,  32,   0,  32, 1);
        else if (idx < WOFF_WHH)    conv_frag(idx - WOFF_WIH,    wih,   wsw + WOFF_WIH,    1,  32,   0,  32, 1);
        else if (idx < WOFF_FC4)    conv_frag(idx - WOFF_WHH,    whh,   wsw + WOFF_WHH,    1,  32,   0,  32, 0);
        else                        conv_frag(idx - WOFF_FC4,    fc4w,  wsw + WOFF_FC4,    1,  32,   0,  32, 1);
    } else if (idx < WTOT + BTOT) {
        int bi = idx - WTOT;
        float v;
        if      (bi < 128) v = fc1b[bi];
        else if (bi < 256) v = fc1ab[bi - 128];
        else if (bi < 384) v = fc1bb[bi - 256];
        else if (bi < 448) {            // fold fc1c_w[:,128:140] @ w_game into bias
            int n = bi - 384;
            v = fc1cb[n];
            for (int q = 0; q < 12; ++q) v += fc1cw[n * 140 + 128 + q] * wgame[q];
        }
        else if (bi < 480) v = fc2b[bi - 448];
        else if (bi < 512) v = fc3b[bi - 480];
        else if (bi < 640) { int n = bi - 512; v = bih[n] + bhh[n]; }   // fused LSTM bias
        else               v = fc4b[bi - 640];
        wsb[bi] = v;
    }
}

// ---------------------------------------------------------------------------
// Helpers
// ---------------------------------------------------------------------------
__device__ __forceinline__ bf16x8 ld8f(const float* __restrict__ p) {
    f32x4 a = *(const f32x4*)p;
    f32x4 b = *(const f32x4*)(p + 4);
    bf16x8 r;
    r[0] = (__bf16)a[0]; r[1] = (__bf16)a[1]; r[2] = (__bf16)a[2]; r[3] = (__bf16)a[3];
    r[4] = (__bf16)b[0]; r[5] = (__bf16)b[1]; r[6] = (__bf16)b[2]; r[7] = (__bf16)b[3];
    return r;
}

__device__ __forceinline__ bf16x8 ld4f_masked(const float* __restrict__ p, bool on) {
    f32x4 v = {0.f, 0.f, 0.f, 0.f};
    if (on) v = *(const f32x4*)p;
    bf16x8 r;
    r[0] = (__bf16)v[0]; r[1] = (__bf16)v[1]; r[2] = (__bf16)v[2]; r[3] = (__bf16)v[3];
    r[4] = (__bf16)0.f;  r[5] = (__bf16)0.f;  r[6] = (__bf16)0.f;  r[7] = (__bf16)0.f;
    return r;
}

// pack acc[2s],acc[2s+1] (n = 16t+4g+r) into next-layer B-frag, with relu
__device__ __forceinline__ bf16x8 packrelu(const f32x4* a, int s) {
    bf16x8 r;
#pragma unroll
    for (int j = 0; j < 8; ++j) {
        float v = a[2 * s + (j >> 2)][j & 3];
        r[j] = (__bf16)fmaxf(v, 0.f);
    }
    return r;
}

__device__ __forceinline__ float sigm(float v)  { return 1.f / (1.f + __expf(-v)); }
__device__ __forceinline__ float tanh_(float v) { return 1.f - 2.f / (1.f + __expf(2.f * v)); }

// ---------------------------------------------------------------------------
// K2: L1 only. x[256] -> h1 frags. FC1 in 64KB LDS. M=2, 8 waves, grid 512.
// ---------------------------------------------------------------------------
__global__ __launch_bounds__(512, 2) void k_l1(
        const float* __restrict__ x, const __bf16* __restrict__ wsw,
        const float* __restrict__ wsb, __bf16* __restrict__ h1ws) {
    __shared__ __align__(16) __bf16 slds[32768];   // 64 KB (FC1)
    const int tid  = threadIdx.x;
    const int lane = tid & 63;
    const int wv   = tid >> 6;
    const int gq   = lane >> 4;
    const int mr   = lane & 15;
    {
        const i32x4* gs = (const i32x4*)(wsw + WOFF_FC1);
        i32x4*       sd = (i32x4*)slds;
#pragma unroll
        for (int i = 0; i < 8; ++i) sd[i * 512 + tid] = gs[i * 512 + tid];
    }
    __syncthreads();
    const bf16x8* Wfc1 = (const bf16x8*)slds;

    const int rowbase = blockIdx.x * 256 + wv * 32;
    const int rowA = rowbase + mr, rowB = rowA + 16;
    f32x4 aA[8], aB[8];
#pragma unroll
    for (int t = 0; t < 8; ++t) {
        f32x4 bv = *(const f32x4*)(wsb + BOFF_FC1 + 16 * t + 4 * gq);
        aA[t] = bv; aB[t] = bv;
    }
    const float* xrA = x + rowA * 256 + 8 * gq;
    const float* xrB = x + rowB * 256 + 8 * gq;
#pragma unroll
    for (int p = 0; p < 4; ++p) {
        bf16x8 a0A = ld8f(xrA + 64 * p);
        bf16x8 a0B = ld8f(xrB + 64 * p);
        bf16x8 a1A = ld8f(xrA + 64 * p + 32);
        bf16x8 a1B = ld8f(xrB + 64 * p + 32);
#pragma unroll
        for (int t = 0; t < 8; ++t) {
            bf16x8 wf = Wfc1[(t * 8 + 2 * p) * 64 + lane];
            aA[t] = MFMA16(wf, a0A, aA[t]);
            aB[t] = MFMA16(wf, a0B, aB[t]);
        }
#pragma unroll
        for (int t = 0; t < 8; ++t) {
            bf16x8 wf = Wfc1[(t * 8 + 2 * p + 1) * 64 + lane];
            aA[t] = MFMA16(wf, a1A, aA[t]);
            aB[t] = MFMA16(wf, a1B, aB[t]);
        }
    }
    const int rb = rowbase >> 4;                  // rowblock of rowA; rowB = rb+1
#pragma unroll
    for (int s = 0; s < 4; ++s) {
        *(bf16x8*)(h1ws + ((rb * 4 + s) * 512)       + lane * 8) = packrelu(aA, s);
        *(bf16x8*)(h1ws + (((rb + 1) * 4 + s) * 512) + lane * 8) = packrelu(aB, s);
    }
}

// ---------------------------------------------------------------------------
// K3: L1A + L1B. h1(+w) -> h3 frags. 80KB LDS. M=2, 8 waves, grid 512.
// ---------------------------------------------------------------------------
__global__ __launch_bounds__(512, 2) void k_l1ab(
        const float* __restrict__ w, const __bf16* __restrict__ wsw,
        const float* __restrict__ wsb, const __bf16* __restrict__ h1ws,
        __bf16* __restrict__ h3ws) {
    __shared__ __align__(16) __bf16 slds[40960];   // 80 KB
    const int tid  = threadIdx.x;
    const int lane = tid & 63;
    const int wv   = tid >> 6;
    const int gq   = lane >> 4;
    const int mr   = lane & 15;
    const int rowbase = blockIdx.x * 256 + wv * 32;
    const int rowA = rowbase + mr, rowB = rowA + 16;
    const int rb = rowbase >> 4;

    // issue global activation loads first (overlap LDS staging)
    bf16x8 h1fA[4], h1fB[4];
#pragma unroll
    for (int s = 0; s < 4; ++s) {
        h1fA[s] = *(const bf16x8*)(h1ws + ((rb * 4 + s) * 512)       + lane * 8);
        h1fB[s] = *(const bf16x8*)(h1ws + (((rb + 1) * 4 + s) * 512) + lane * 8);
    }
    bf16x8 wxa0 = ld8f(w + rowA * 36 + 8 * gq);
    bf16x8 wxb0 = ld8f(w + rowB * 36 + 8 * gq);
    bf16x8 wxa1 = ld4f_masked(w + rowA * 36 + 32, gq == 0);
    bf16x8 wxb1 = ld4f_masked(w + rowB * 36 + 32, gq == 0);

    {   // FC1A_H + FC1B contiguous (32768 elems), then FC1A_W (8192)
        const i32x4* g1 = (const i32x4*)(wsw + WOFF_FC1A_H);
        const i32x4* g2 = (const i32x4*)(wsw + WOFF_FC1A_W);
        i32x4*       sd = (i32x4*)slds;
#pragma unroll
        for (int i = 0; i < 8; ++i) sd[i * 512 + tid] = g1[i * 512 + tid];
#pragma unroll
        for (int i = 0; i < 2; ++i) sd[4096 + i * 512 + tid] = g2[i * 512 + tid];
    }
    __syncthreads();
    const bf16x8* Wf1aH = (const bf16x8*)(slds);            // 16384 elems
    const bf16x8* Wfc1b = (const bf16x8*)(slds + 16384);    // 16384 elems
    const bf16x8* Wf1aW = (const bf16x8*)(slds + 32768);    // 8192 elems

    // ---- L1A ----
    f32x4 aA[8], aB[8];
#pragma unroll
    for (int t = 0; t < 8; ++t) {
        f32x4 bv = *(const f32x4*)(wsb + BOFF_FC1A + 16 * t + 4 * gq);
        aA[t] = bv; aB[t] = bv;
    }
#pragma unroll
    for (int s = 0; s < 4; ++s)
#pragma unroll
        for (int t = 0; t < 8; ++t) {
            bf16x8 wf = Wf1aH[(t * 4 + s) * 64 + lane];
            aA[t] = MFMA16(wf, h1fA[s], aA[t]);
            aB[t] = MFMA16(wf, h1fB[s], aB[t]);
        }
#pragma unroll
    for (int t = 0; t < 8; ++t) {
        bf16x8 wf0 = Wf1aW[(t * 2 + 0) * 64 + lane];
        bf16x8 wf1 = Wf1aW[(t * 2 + 1) * 64 + lane];
        aA[t] = MFMA16(wf0, wxa0, aA[t]);
        aB[t] = MFMA16(wf0, wxb0, aB[t]);
        aA[t] = MFMA16(wf1, wxa1, aA[t]);
        aB[t] = MFMA16(wf1, wxb1, aB[t]);
    }
    bf16x8 h2fA[4], h2fB[4];
#pragma unroll
    for (int s = 0; s < 4; ++s) { h2fA[s] = packrelu(aA, s); h2fB[s] = packrelu(aB, s); }

    // ---- L1B ----
    f32x4 bA[8], bB[8];
#pragma unroll
    for (int t = 0; t < 8; ++t) {
        f32x4 bv = *(const f32x4*)(wsb + BOFF_FC1B + 16 * t + 4 * gq);
        bA[t] = bv; bB[t] = bv;
    }
#pragma unroll
    for (int s = 0; s < 4; ++s)
#pragma unroll
        for (int t = 0; t < 8; ++t) {
            bf16x8 wf = Wfc1b[(t * 4 + s) * 64 + lane];
            bA[t] = MFMA16(wf, h2fA[s], bA[t]);
            bB[t] = MFMA16(wf, h2fB[s], bB[t]);
        }
#pragma unroll
    for (int s = 0; s < 4; ++s) {
        *(bf16x8*)(h3ws + ((rb * 4 + s) * 512)       + lane * 8) = packrelu(bA, s);
        *(bf16x8*)(h3ws + (((rb + 1) * 4 + s) * 512) + lane * 8) = packrelu(bB, s);
    }
}

// ---------------------------------------------------------------------------
// K4: tail. h3 -> out. FC1C/FC2/FC3/WIH/WHH/FC4 in 56KB LDS. M=2, grid 512.
// ---------------------------------------------------------------------------
__global__ __launch_bounds__(512, 2) void k_tail(
        const float* __restrict__ h0, const float* __restrict__ c0,
        const float* __restrict__ fc5w, const float* __restrict__ fc5b,
        const __bf16* __restrict__ wsw, const float* __restrict__ wsb,
        const __bf16* __restrict__ h3ws, float* __restrict__ out) {
    __shared__ __align__(16) __bf16 slds[28672];   // 56 KB = wsw[65536..94208]
    const int tid  = threadIdx.x;
    const int lane = tid & 63;
    const int wv   = tid >> 6;
    const int gq   = lane >> 4;
    const int mr   = lane & 15;
    const int rowbase = blockIdx.x * 256 + wv * 32;
    const int rowA = rowbase + mr, rowB = rowA + 16;
    const int rb = rowbase >> 4;

    // issue global loads first (overlap staging)
    bf16x8 h3fA[4], h3fB[4];
#pragma unroll
    for (int s = 0; s < 4; ++s) {
        h3fA[s] = *(const bf16x8*)(h3ws + ((rb * 4 + s) * 512)       + lane * 8);
        h3fB[s] = *(const bf16x8*)(h3ws + (((rb + 1) * 4 + s) * 512) + lane * 8);
    }
    bf16x8 h0fA = ld8f(h0 + rowA * 32 + 8 * gq);
    bf16x8 h0fB = ld8f(h0 + rowB * 32 + 8 * gq);
    f32x4  cA0 = *(const f32x4*)(c0 + rowA * 32 + 4 * gq);
    f32x4  cA1 = *(const f32x4*)(c0 + rowA * 32 + 16 + 4 * gq);
    f32x4  cB0 = *(const f32x4*)(c0 + rowB * 32 + 4 * gq);
    f32x4  cB1 = *(const f32x4*)(c0 + rowB * 32 + 16 + 4 * gq);

    {   // stage wsw[65536..94208] = 28672 elems = 3584 x16B -> 7/thread
        const i32x4* gs = (const i32x4*)(wsw + WOFF_FC1C);
        i32x4*       sd = (i32x4*)slds;
#pragma unroll
        for (int i = 0; i < 7; ++i) sd[i * 512 + tid] = gs[i * 512 + tid];
    }
    __syncthreads();
    const bf16x8* Wfc1c = (const bf16x8*)(slds);            // 0
    const bf16x8* Wfc2  = (const bf16x8*)(slds + 16384);    // 81920-65536
    const bf16x8* Wfc3  = (const bf16x8*)(slds + 18432);
    const bf16x8* Wwih  = (const bf16x8*)(slds + 19456);
    const bf16x8* Wwhh  = (const bf16x8*)(slds + 23552);
    const bf16x8* Wfc4  = (const bf16x8*)(slds + 27648);

    // ---- L1C: h3 -> h4[64] ----
    bf16x8 h4fA[2], h4fB[2];
    {
        f32x4 aA[4], aB[4];
#pragma unroll
        for (int t = 0; t < 4; ++t) {
            f32x4 bv = *(const f32x4*)(wsb + BOFF_FC1C + 16 * t + 4 * gq);
            aA[t] = bv; aB[t] = bv;
        }
#pragma unroll
        for (int s = 0; s < 4; ++s)
#pragma unroll
            for (int t = 0; t < 4; ++t) {
                bf16x8 wf = Wfc1c[(t * 4 + s) * 64 + lane];
                aA[t] = MFMA16(wf, h3fA[s], aA[t]);
                aB[t] = MFMA16(wf, h3fB[s], aB[t]);
            }
#pragma unroll
        for (int s = 0; s < 2; ++s) { h4fA[s] = packrelu(aA, s); h4fB[s] = packrelu(aB, s); }
    }
    // ---- L2: h4 -> h5[32] ----
    bf16x8 h5fA, h5fB;
    {
        f32x4 aA[2], aB[2];
#pragma unroll
        for (int t = 0; t < 2; ++t) {
            f32x4 bv = *(const f32x4*)(wsb + BOFF_FC2 + 16 * t + 4 * gq);
            aA[t] = bv; aB[t] = bv;
        }
#pragma unroll
        for (int s = 0; s < 2; ++s)
#pragma unroll
            for (int t = 0; t < 2; ++t) {
                bf16x8 wf = Wfc2[(t * 2 + s) * 64 + lane];
                aA[t] = MFMA16(wf, h4fA[s], aA[t]);
                aB[t] = MFMA16(wf, h4fB[s], aB[t]);
            }
        h5fA = packrelu(aA, 0); h5fB = packrelu(aB, 0);
    }
    // ---- L3: h5 -> h6[32] ----
    bf16x8 h6fA, h6fB;
    {
        f32x4 aA[2], aB[2];
#pragma unroll
        for (int t = 0; t < 2; ++t) {
            f32x4 bv = *(const f32x4*)(wsb + BOFF_FC3 + 16 * t + 4 * gq);
            aA[t] = bv; aB[t] = bv;
        }
#pragma unroll
        for (int t = 0; t < 2; ++t) {
            bf16x8 wf = Wfc3[t * 64 + lane];
            aA[t] = MFMA16(wf, h5fA, aA[t]);
            aB[t] = MFMA16(wf, h5fB, aB[t]);
        }
        h6fA = packrelu(aA, 0); h6fB = packrelu(aB, 0);
    }
    // ---- LSTM gates ----
    bf16x8 hnfA, hnfB;
    {
        f32x4 gA[8], gB[8];
#pragma unroll
        for (int t = 0; t < 8; ++t) {
            f32x4 bv = *(const f32x4*)(wsb + BOFF_LSTM + 16 * t + 4 * gq);
            gA[t] = bv; gB[t] = bv;
        }
#pragma unroll
        for (int t = 0; t < 8; ++t) {
            bf16x8 wf = Wwih[t * 64 + lane];
            gA[t] = MFMA16(wf, h6fA, gA[t]);
            gB[t] = MFMA16(wf, h6fB, gB[t]);
        }
#pragma unroll
        for (int t = 0; t < 8; ++t) {
            bf16x8 wf = Wwhh[t * 64 + lane];
            gA[t] = MFMA16(wf, h0fA, gA[t]);
            gB[t] = MFMA16(wf, h0fB, gB[t]);
        }
        // gate tiles: i -> {0,1}, f -> {2,3}, g -> {4,5}, o -> {6,7}
#pragma unroll
        for (int t2 = 0; t2 < 2; ++t2) {
            f32x4 ccA = t2 ? cA1 : cA0;
            f32x4 ccB = t2 ? cB1 : cB0;
#pragma unroll
            for (int r = 0; r < 4; ++r) {
                float cnA = sigm(gA[2 + t2][r]) * ccA[r] + sigm(gA[t2][r]) * tanh_(gA[4 + t2][r]);
                float cnB = sigm(gB[2 + t2][r]) * ccB[r] + sigm(gB[t2][r]) * tanh_(gB[4 + t2][r]);
                hnfA[t2 * 4 + r] = (__bf16)(sigm(gA[6 + t2][r]) * tanh_(cnA));
                hnfB[t2 * 4 + r] = (__bf16)(sigm(gB[6 + t2][r]) * tanh_(cnB));
            }
        }
    }
    // ---- L4 + L5 + sigmoid ----
    f32x4 oA[2], oB[2];
#pragma unroll
    for (int t = 0; t < 2; ++t) {
        f32x4 bv = *(const f32x4*)(wsb + BOFF_FC4 + 16 * t + 4 * gq);
        oA[t] = bv; oB[t] = bv;
    }
#pragma unroll
    for (int t = 0; t < 2; ++t) {
        bf16x8 wf = Wfc4[t * 64 + lane];
        oA[t] = MFMA16(wf, hnfA, oA[t]);
        oB[t] = MFMA16(wf, hnfB, oB[t]);
    }
    f32x4 w5a = *(const f32x4*)(fc5w + 4 * gq);
    f32x4 w5b = *(const f32x4*)(fc5w + 16 + 4 * gq);
    float b5  = fc5b[0];
    float pA = 0.f, pB = 0.f;
#pragma unroll
    for (int r = 0; r < 4; ++r) {
        pA += fmaxf(oA[0][r], 0.f) * w5a[r];
        pA += fmaxf(oA[1][r], 0.f) * w5b[r];
        pB += fmaxf(oB[0][r], 0.f) * w5a[r];
        pB += fmaxf(oB[1][r], 0.f) * w5b[r];
    }
    pA += __shfl_xor(pA, 16); pA += __shfl_xor(pA, 32);
    pB += __shfl_xor(pB, 16); pB += __shfl_xor(pB, 32);
    float resA = sigm(pA + b5);
    float resB = sigm(pB + b5);
    if (lane < 16) {
        out[rowbase + lane]      = resA;
        out[rowbase + 16 + lane] = resB;
    }
}

// ---------------------------------------------------------------------------
// Fallback: v12 fused kernel (session best 61.4us) if ws too small.
// ---------------------------------------------------------------------------
#define LDS_ELEMS 73728
__global__ __launch_bounds__(1024, 4) void fused_mlp_lstm(
        const float* __restrict__ x,  const float* __restrict__ w,
        const float* __restrict__ h0, const float* __restrict__ c0,
        const float* __restrict__ fc5w, const float* __restrict__ fc5b,
        const __bf16* __restrict__ wsw, const float* __restrict__ wsb,
        float* __restrict__ out) {
    __shared__ __align__(16) __bf16 slds[LDS_ELEMS];   // 144 KB
    const int tid     = threadIdx.x;
    const int lane    = tid & 63;
    const int gq      = lane >> 4;
    const int mr      = lane & 15;
    const int rowbase = blockIdx.x * 256 + (tid >> 6) * 16;
    const int row     = rowbase + mr;
    {
        const i32x4* gs = (const i32x4*)wsw;
        i32x4*       sd = (i32x4*)slds;
#pragma unroll
        for (int i = 0; i < 9; ++i) sd[i * 1024 + tid] = gs[i * 1024 + tid];
    }
    __syncthreads();
    const bf16x8* Wfc1  = (const bf16x8*)(slds + WOFF_FC1);
    const bf16x8* Wf1aH = (const bf16x8*)(slds + WOFF_FC1A_H);
    const bf16x8* Wfc1b = (const bf16x8*)(slds + WOFF_FC1B);
    const bf16x8* Wfc1c = (const bf16x8*)(slds + WOFF_FC1C);
    const bf16x8* Wf1aW = (const bf16x8*)(wsw + WOFF_FC1A_W);
    const bf16x8* Wfc2  = (const bf16x8*)(wsw + WOFF_FC2);
    const bf16x8* Wfc3  = (const bf16x8*)(wsw + WOFF_FC3);
    const bf16x8* Wwih  = (const bf16x8*)(wsw + WOFF_WIH);
    const bf16x8* Wwhh  = (const bf16x8*)(wsw + WOFF_WHH);
    const bf16x8* Wfc4  = (const bf16x8*)(wsw + WOFF_FC4);
    bf16x8 h1f[4];
    {
        f32x4 acc1[8];
#pragma unroll
        for (int t = 0; t < 8; ++t)
            acc1[t] = *(const f32x4*)(wsb + BOFF_FC1 + 16 * t + 4 * gq);
        const float* xrow = x + row * 256 + 8 * gq;
#pragma unroll
        for (int p = 0; p < 4; ++p) {
            bf16x8 a0 = ld8f(xrow + 64 * p);
            bf16x8 a1 = ld8f(xrow + 64 * p + 32);
#pragma unroll
            for (int t = 0; t < 8; ++t)
                acc1[t] = MFMA16(Wfc1[(t * 8 + 2 * p) * 64 + lane], a0, acc1[t]);
#pragma unroll
            for (int t = 0; t < 8; ++t)
                acc1[t] = MFMA16(Wfc1[(t * 8 + 2 * p + 1) * 64 + lane], a1, acc1[t]);
        }
#pragma unroll
        for (int s = 0; s < 4; ++s) h1f[s] = packrelu(acc1, s);
    }
    bf16x8 h2f[4];
    {
        bf16x8 wxa0 = ld8f(w + row * 36 + 8 * gq);
        bf16x8 wxa1 = ld4f_masked(w + row * 36 + 32, gq == 0);
        f32x4 acc2[8];
#pragma unroll
        for (int t = 0; t < 8; ++t)
            acc2[t] = *(const f32x4*)(wsb + BOFF_FC1A + 16 * t + 4 * gq);
#pragma unroll
        for (int s = 0; s < 4; ++s)
#pragma unroll
            for (int t = 0; t < 8; ++t)
                acc2[t] = MFMA16(Wf1aH[(t * 4 + s) * 64 + lane], h1f[s], acc2[t]);
#pragma unroll
        for (int t = 0; t < 8; ++t) {
            acc2[t] = MFMA16(Wf1aW[(t * 2 + 0) * 64 + lane], wxa0, acc2[t]);
            acc2[t] = MFMA16(Wf1aW[(t * 2 + 1) * 64 + lane], wxa1, acc2[t]);
        }
#pragma unroll
        for (int s = 0; s < 4; ++s) h2f[s] = packrelu(acc2, s);
    }
    bf16x8 h3f[4];
    {
        f32x4 acc3[8];
#pragma unroll
        for (int t = 0; t < 8; ++t)
            acc3[t] = *(const f32x4*)(wsb + BOFF_FC1B + 16 * t + 4 * gq);
#pragma unroll
        for (int s = 0; s < 4; ++s)
#pragma unroll
            for (int t = 0; t < 8; ++t)
                acc3[t] = MFMA16(Wfc1b[(t * 4 + s) * 64 + lane], h2f[s], acc3[t]);
#pragma unroll
        for (int s = 0; s < 4; ++s) h3f[s] = packrelu(acc3, s);
    }
    bf16x8 h0f  = ld8f(h0 + row * 32 + 8 * gq);
    f32x4  c0r0 = *(const f32x4*)(c0 + row * 32 + 4 * gq);
    f32x4  c0r1 = *(const f32x4*)(c0 + row * 32 + 16 + 4 * gq);
    bf16x8 h4f[2];
    {
        f32x4 acc4[4];
#pragma unroll
        for (int t = 0; t < 4; ++t)
            acc4[t] = *(const f32x4*)(wsb + BOFF_FC1C + 16 * t + 4 * gq);
#pragma unroll
        for (int s = 0; s < 4; ++s)
#pragma unroll
            for (int t = 0; t < 4; ++t)
                acc4[t] = MFMA16(Wfc1c[(t * 4 + s) * 64 + lane], h3f[s], acc4[t]);
#pragma unroll
        for (int s = 0; s < 2; ++s) h4f[s] = packrelu(acc4, s);
    }
    bf16x8 h5f;
    {
        f32x4 acc5[2];
#pragma unroll
        for (int t = 0; t < 2; ++t)
            acc5[t] = *(const f32x4*)(wsb + BOFF_FC2 + 16 * t + 4 * gq);
#pragma unroll
        for (int s = 0; s < 2; ++s)
#pragma unroll
            for (int t = 0; t < 2; ++t)
                acc5[t] = MFMA16(Wfc2[(t * 2 + s) * 64 + lane], h4f[s], acc5[t]);
        h5f = packrelu(acc5, 0);
    }
    bf16x8 h6f;
    {
        f32x4 acc6[2];
#pragma unroll
        for (int t = 0; t < 2; ++t)
            acc6[t] = *(const f32x4*)(wsb + BOFF_FC3 + 16 * t + 4 * gq);
#pragma unroll
        for (int t = 0; t < 2; ++t)
            acc6[t] = MFMA16(Wfc3[t * 64 + lane], h5f, acc6[t]);
        h6f = packrelu(acc6, 0);
    }
    bf16x8 hnf;
    {
        f32x4 accg[8];
#pragma unroll
        for (int t = 0; t < 8; ++t)
            accg[t] = *(const f32x4*)(wsb + BOFF_LSTM + 16 * t + 4 * gq);
#pragma unroll
        for (int t = 0; t < 8; ++t)
            accg[t] = MFMA16(Wwih[t * 64 + lane], h6f, accg[t]);
#pragma unroll
        for (int t = 0; t < 8; ++t)
            accg[t] = MFMA16(Wwhh[t * 64 + lane], h0f, accg[t]);
#pragma unroll
        for (int t2 = 0; t2 < 2; ++t2) {
            f32x4 cc = t2 ? c0r1 : c0r0;
#pragma unroll
            for (int r = 0; r < 4; ++r) {
                float ig = accg[t2][r];
                float fg = accg[2 + t2][r];
                float gg = accg[4 + t2][r];
                float og = accg[6 + t2][r];
                float cn = sigm(fg) * cc[r] + sigm(ig) * tanh_(gg);
                hnf[t2 * 4 + r] = (__bf16)(sigm(og) * tanh_(cn));
            }
        }
    }
    f32x4 acco[2];
#pragma unroll
    for (int t = 0; t < 2; ++t)
        acco[t] = *(const f32x4*)(wsb + BOFF_FC4 + 16 * t + 4 * gq);
#pragma unroll
    for (int t = 0; t < 2; ++t)
        acco[t] = MFMA16(Wfc4[t * 64 + lane], hnf, acco[t]);
    f32x4 w5a = *(const f32x4*)(fc5w + 4 * gq);
    f32x4 w5b = *(const f32x4*)(fc5w + 16 + 4 * gq);
    float p = 0.f;
#pragma unroll
    for (int r = 0; r < 4; ++r) {
        p += fmaxf(acco[0][r], 0.f) * w5a[r];
        p += fmaxf(acco[1][r], 0.f) * w5b[r];
    }
    p += __shfl_xor(p, 16);
    p += __shfl_xor(p, 32);
    float res = sigm(p + fc5b[0]);
    if (lane < 16) out[rowbase + lane] = res;
}

// ---------------------------------------------------------------------------
extern "C" void kernel_launch(void* const* d_in, const int* in_sizes, int n_in,
                              void* d_out, int out_size, void* d_ws, size_t ws_size,
                              hipStream_t stream) {
    const float* x     = (const float*)d_in[0];
    const float* w     = (const float*)d_in[1];
    const float* h0    = (const float*)d_in[2];
    const float* c0    = (const float*)d_in[3];
    const float* fc1w  = (const float*)d_in[4];
    const float* fc1b  = (const float*)d_in[5];
    const float* fc1aw = (const float*)d_in[6];
    const float* fc1ab = (const float*)d_in[7];
    const float* fc1bw = (const float*)d_in[8];
    const float* fc1bb = (const float*)d_in[9];
    const float* wgame = (const float*)d_in[10];
    const float* fc1cw = (const float*)d_in[11];
    const float* fc1cb = (const float*)d_in[12];
    const float* fc2w  = (const float*)d_in[13];
    const float* fc2b  = (const float*)d_in[14];
    const float* fc3w  = (const float*)d_in[15];
    const float* fc3b  = (const float*)d_in[16];
    const float* wih   = (const float*)d_in[17];
    const float* whh   = (const float*)d_in[18];
    const float* bih   = (const float*)d_in[19];
    const float* bhh   = (const float*)d_in[20];
    const float* fc4w  = (const float*)d_in[21];
    const float* fc4b  = (const float*)d_in[22];
    const float* fc5w  = (const float*)d_in[23];
    const float* fc5b  = (const float*)d_in[24];

    __bf16* wsw = (__bf16*)d_ws;
    float*  wsb = (float*)((char*)d_ws + WTOT * sizeof(__bf16));
    (void)n_in; (void)out_size;

    const int Btot = in_sizes[0] / 256;   // 131072 rows

    prep_kernel<<<(WTOT + BTOT + 255) / 256, 256, 0, stream>>>(
        fc1w, fc1b, fc1aw, fc1ab, fc1bw, fc1bb, wgame, fc1cw, fc1cb,
        fc2w, fc2b, fc3w, fc3b, wih, whh, bih, bhh, fc4w, fc4b, wsw, wsb);

    if (ws_size >= WS_REQUIRED) {
        __bf16* h1ws = (__bf16*)((char*)d_ws + H1_BYTE_OFF);
        __bf16* h3ws = (__bf16*)((char*)d_ws + H1_BYTE_OFF + HACT_BYTES);
        k_l1  <<<Btot / 256, 512, 0, stream>>>(x, wsw, wsb, h1ws);
        k_l1ab<<<Btot / 256, 512, 0, stream>>>(w, wsw, wsb, h1ws, h3ws);
        k_tail<<<Btot / 256, 512, 0, stream>>>(h0, c0, fc5w, fc5b, wsw, wsb, h3ws, (float*)d_out);
    } else {
        fused_mlp_lstm<<<Btot / 256, 1024, 0, stream>>>(
            x, w, h0, c0, fc5w, fc5b, wsw, wsb, (float*)d_out);
    }
}

// Round 26
// 61.423 us; speedup vs baseline: 1.4278x; 1.4278x over previous
//
#include <hip/hip_runtime.h>
#include <hip/hip_bf16.h>

// ---------------------------------------------------------------------------
// Fused MLP+LSTM for B=131072 rows, FINAL = v12 (session best: 61.4 us).
// 1024-thread blocks (16 waves, 4 waves/SIMD, 128 unified regs/wave),
// ONE 16-row chain per wave (256 rows/block), grid = 512. ALL four fat
// weight layers in 144 KB LDS (staged once per block). Chain body is the
// v8-proven no-spill structure: x pair-streamed in L1 (2 loads in flight,
// static indices), h0/c0 deferred to L1c, acc <=32 AGPR, all loops static.
// Operand-swapped MFMA chain: D = W*act^T keeps batch row at lane&15, so
// every layer-to-layer handoff is a lane-local register repack.
// Session: 169 -> 61.4 us. Plateau = structural latency equilibrium
// (64 rows/SIMD register-file cap x serial 9-layer chain). Tested & nulled:
// TLP (2/3/4/6 w/SIMD), M=1/2, LDS splits 48-144KB, dbuf-ILP, weight-
// stationary, wave-pipeline, setprio, chain-split kernels (ws-fill cost).
// ---------------------------------------------------------------------------

typedef __bf16 bf16x8 __attribute__((ext_vector_type(8)));
typedef float  f32x4  __attribute__((ext_vector_type(4)));
typedef int    i32x4  __attribute__((ext_vector_type(4)));

#define MFMA16(A, B, C) __builtin_amdgcn_mfma_f32_16x16x32_bf16((A), (B), (C), 0, 0, 0)

// fragment-element offsets (bf16 elems). [0, LDS_ELEMS) staged to LDS.
#define WOFF_FC1    0
#define WOFF_FC1A_H 32768
#define WOFF_FC1B   49152
#define WOFF_FC1C   65536
#define LDS_ELEMS   73728          // 147456 B = 144 KB
#define WOFF_FC1A_W 73728
#define WOFF_FC2    81920
#define WOFF_FC3    83968
#define WOFF_WIH    84992
#define WOFF_WHH    89088
#define WOFF_FC4    93184
#define WTOT        94208
// bias offsets (floats, after bf16 region in ws)
#define BOFF_FC1  0
#define BOFF_FC1A 128
#define BOFF_FC1B 256
#define BOFF_FC1C 384
#define BOFF_FC2  448
#define BOFF_FC3  480
#define BOFF_LSTM 512
#define BOFF_FC4  640
#define BTOT      672

// ---------------------------------------------------------------------------
// Fragment mapping (verified since v1):
//   rel -> j = rel&7, lane = (rel>>3)&63, fs = rel>>9, s = fs%ns, t = fs/ns,
//   gq = lane>>4, n = 16t + (lane&15),
//   k = perm ? 16*(2s + (j>>2)) + 4*gq + (j&3) : 32*s + 8*gq + j
// ---------------------------------------------------------------------------
__device__ __forceinline__ void conv_frag(int rel, const float* __restrict__ src,
                                          __bf16* __restrict__ dst,
                                          int ns, int Krow, int kbase, int klim, int perm) {
    int j    = rel & 7;
    int lane = (rel >> 3) & 63;
    int fs   = rel >> 9;
    int s    = fs % ns;
    int t    = fs / ns;
    int gq   = lane >> 4;
    int n    = 16 * t + (lane & 15);
    int k    = perm ? (16 * (2 * s + (j >> 2)) + 4 * gq + (j & 3))
                    : (32 * s + 8 * gq + j);
    float v  = (k < klim) ? src[n * Krow + kbase + k] : 0.f;
    dst[rel] = (__bf16)v;
}

// ---------------------------------------------------------------------------
// Prep: full fp32 -> bf16 fragment conversion + bias folding (runs once).
// ---------------------------------------------------------------------------
__global__ void prep_kernel(const float* __restrict__ fc1w,  const float* __restrict__ fc1b,
                            const float* __restrict__ fc1aw, const float* __restrict__ fc1ab,
                            const float* __restrict__ fc1bw, const float* __restrict__ fc1bb,
                            const float* __restrict__ wgame, const float* __restrict__ fc1cw,
                            const float* __restrict__ fc1cb, const float* __restrict__ fc2w,
                            const float* __restrict__ fc2b,  const float* __restrict__ fc3w,
                            const float* __restrict__ fc3b,  const float* __restrict__ wih,
                            const float* __restrict__ whh,   const float* __restrict__ bih,
                            const float* __restrict__ bhh,   const float* __restrict__ fc4w,
                            const float* __restrict__ fc4b,
                            __bf16* __restrict__ wsw, float* __restrict__ wsb) {
    int idx = blockIdx.x * 256 + threadIdx.x;
    if (idx < WTOT) {
        if      (idx < WOFF_FC1A_H) conv_frag(idx - WOFF_FC1,    fc1w,  wsw + WOFF_FC1,    8, 256,   0, 256, 0);
        else if (idx < WOFF_FC1B)   conv_frag(idx - WOFF_FC1A_H, fc1aw, wsw + WOFF_FC1A_H, 4, 164,   0, 128, 1);
        else if (idx < WOFF_FC1C)   conv_frag(idx - WOFF_FC1B,   fc1bw, wsw + WOFF_FC1B,   4, 128,   0, 128, 1);
        else if (idx < WOFF_FC1A_W) conv_frag(idx - WOFF_FC1C,   fc1cw, wsw + WOFF_FC1C,   4, 140,   0, 128, 1);
        else if (idx < WOFF_FC2)    conv_frag(idx - WOFF_FC1A_W, fc1aw, wsw + WOFF_FC1A_W, 2, 164, 128,  36, 0);
        else if (idx < WOFF_FC3)    conv_frag(idx - WOFF_FC2,    fc2w,  wsw + WOFF_FC2,    2,  64,   0,  64, 1);
        else if (idx < WOFF_WIH)    conv_frag(idx - WOFF_FC3,    fc3w,  wsw + WOFF_FC3,    1,  32,   0,  32, 1);
        else if (idx < WOFF_WHH)    conv_frag(idx - WOFF_WIH,    wih,   wsw + WOFF_WIH,    1,  32,   0,  32, 1);
        else if (idx < WOFF_FC4)    conv_frag(idx - WOFF_WHH,    whh,   wsw + WOFF_WHH,    1,  32,   0,  32, 0);
        else                        conv_frag(idx - WOFF_FC4,    fc4w,  wsw + WOFF_FC4,    1,  32,   0,  32, 1);
    } else if (idx < WTOT + BTOT) {
        int bi = idx - WTOT;
        float v;
        if      (bi < 128) v = fc1b[bi];
        else if (bi < 256) v = fc1ab[bi - 128];
        else if (bi < 384) v = fc1bb[bi - 256];
        else if (bi < 448) {            // fold fc1c_w[:,128:140] @ w_game into bias
            int n = bi - 384;
            v = fc1cb[n];
            for (int q = 0; q < 12; ++q) v += fc1cw[n * 140 + 128 + q] * wgame[q];
        }
        else if (bi < 480) v = fc2b[bi - 448];
        else if (bi < 512) v = fc3b[bi - 480];
        else if (bi < 640) { int n = bi - 512; v = bih[n] + bhh[n]; }   // fused LSTM bias
        else               v = fc4b[bi - 640];
        wsb[bi] = v;
    }
}

// ---------------------------------------------------------------------------
// Helpers
// ---------------------------------------------------------------------------
__device__ __forceinline__ bf16x8 ld8f(const float* __restrict__ p) {
    f32x4 a = *(const f32x4*)p;
    f32x4 b = *(const f32x4*)(p + 4);
    bf16x8 r;
    r[0] = (__bf16)a[0]; r[1] = (__bf16)a[1]; r[2] = (__bf16)a[2]; r[3] = (__bf16)a[3];
    r[4] = (__bf16)b[0]; r[5] = (__bf16)b[1]; r[6] = (__bf16)b[2]; r[7] = (__bf16)b[3];
    return r;
}

__device__ __forceinline__ bf16x8 ld4f_masked(const float* __restrict__ p, bool on) {
    f32x4 v = {0.f, 0.f, 0.f, 0.f};
    if (on) v = *(const f32x4*)p;
    bf16x8 r;
    r[0] = (__bf16)v[0]; r[1] = (__bf16)v[1]; r[2] = (__bf16)v[2]; r[3] = (__bf16)v[3];
    r[4] = (__bf16)0.f;  r[5] = (__bf16)0.f;  r[6] = (__bf16)0.f;  r[7] = (__bf16)0.f;
    return r;
}

// pack acc[2s],acc[2s+1] (n = 16t+4g+r) into next-layer B-frag, with relu
__device__ __forceinline__ bf16x8 packrelu(const f32x4* a, int s) {
    bf16x8 r;
#pragma unroll
    for (int j = 0; j < 8; ++j) {
        float v = a[2 * s + (j >> 2)][j & 3];
        r[j] = (__bf16)fmaxf(v, 0.f);
    }
    return r;
}

__device__ __forceinline__ float sigm(float v)  { return 1.f / (1.f + __expf(-v)); }
__device__ __forceinline__ float tanh_(float v) { return 1.f - 2.f / (1.f + __expf(2.f * v)); }

// ---------------------------------------------------------------------------
// Fused main kernel: 16 waves/block, ONE 16-row chain per wave, 256 rows/blk
// ---------------------------------------------------------------------------
__global__ __launch_bounds__(1024, 4) void fused_mlp_lstm(
        const float* __restrict__ x,  const float* __restrict__ w,
        const float* __restrict__ h0, const float* __restrict__ c0,
        const float* __restrict__ fc5w, const float* __restrict__ fc5b,
        const __bf16* __restrict__ wsw, const float* __restrict__ wsb,
        float* __restrict__ out) {
    __shared__ __align__(16) __bf16 slds[LDS_ELEMS];   // 144 KB

    const int tid     = threadIdx.x;
    const int lane    = tid & 63;
    const int gq      = lane >> 4;
    const int mr      = lane & 15;
    const int rowbase = blockIdx.x * 256 + (tid >> 6) * 16;
    const int row     = rowbase + mr;

    // ---- stage all big weight layers to LDS (9 x 16B per thread) ----------
    {
        const i32x4* gs = (const i32x4*)wsw;
        i32x4*       sd = (i32x4*)slds;
#pragma unroll
        for (int i = 0; i < 9; ++i) sd[i * 1024 + tid] = gs[i * 1024 + tid];
    }
    __syncthreads();

    const bf16x8* Wfc1  = (const bf16x8*)(slds + WOFF_FC1);
    const bf16x8* Wf1aH = (const bf16x8*)(slds + WOFF_FC1A_H);
    const bf16x8* Wfc1b = (const bf16x8*)(slds + WOFF_FC1B);
    const bf16x8* Wfc1c = (const bf16x8*)(slds + WOFF_FC1C);
    const bf16x8* Wf1aW = (const bf16x8*)(wsw + WOFF_FC1A_W);
    const bf16x8* Wfc2  = (const bf16x8*)(wsw + WOFF_FC2);
    const bf16x8* Wfc3  = (const bf16x8*)(wsw + WOFF_FC3);
    const bf16x8* Wwih  = (const bf16x8*)(wsw + WOFF_WIH);
    const bf16x8* Wwhh  = (const bf16x8*)(wsw + WOFF_WHH);
    const bf16x8* Wfc4  = (const bf16x8*)(wsw + WOFF_FC4);

    // ---- L1: x[256] -> h1[128]  (x pair-streamed, 2 loads in flight) ------
    bf16x8 h1f[4];
    {
        f32x4 acc1[8];
#pragma unroll
        for (int t = 0; t < 8; ++t)
            acc1[t] = *(const f32x4*)(wsb + BOFF_FC1 + 16 * t + 4 * gq);
        const float* xrow = x + row * 256 + 8 * gq;
#pragma unroll
        for (int p = 0; p < 4; ++p) {
            bf16x8 a0 = ld8f(xrow + 64 * p);
            bf16x8 a1 = ld8f(xrow + 64 * p + 32);
#pragma unroll
            for (int t = 0; t < 8; ++t)
                acc1[t] = MFMA16(Wfc1[(t * 8 + 2 * p) * 64 + lane], a0, acc1[t]);
#pragma unroll
            for (int t = 0; t < 8; ++t)
                acc1[t] = MFMA16(Wfc1[(t * 8 + 2 * p + 1) * 64 + lane], a1, acc1[t]);
        }
#pragma unroll
        for (int s = 0; s < 4; ++s) h1f[s] = packrelu(acc1, s);
    }

    // ---- L1a: [h1, w] (128+36) -> h2[128] --------------------------------
    bf16x8 h2f[4];
    {
        bf16x8 wxa0 = ld8f(w + row * 36 + 8 * gq);
        bf16x8 wxa1 = ld4f_masked(w + row * 36 + 32, gq == 0);
        f32x4 acc2[8];
#pragma unroll
        for (int t = 0; t < 8; ++t)
            acc2[t] = *(const f32x4*)(wsb + BOFF_FC1A + 16 * t + 4 * gq);
#pragma unroll
        for (int s = 0; s < 4; ++s)
#pragma unroll
            for (int t = 0; t < 8; ++t)
                acc2[t] = MFMA16(Wf1aH[(t * 4 + s) * 64 + lane], h1f[s], acc2[t]);
#pragma unroll
        for (int t = 0; t < 8; ++t) {
            acc2[t] = MFMA16(Wf1aW[(t * 2 + 0) * 64 + lane], wxa0, acc2[t]);
            acc2[t] = MFMA16(Wf1aW[(t * 2 + 1) * 64 + lane], wxa1, acc2[t]);
        }
#pragma unroll
        for (int s = 0; s < 4; ++s) h2f[s] = packrelu(acc2, s);
    }

    // ---- L1b: h2[128] -> h3[128] -----------------------------------------
    bf16x8 h3f[4];
    {
        f32x4 acc3[8];
#pragma unroll
        for (int t = 0; t < 8; ++t)
            acc3[t] = *(const f32x4*)(wsb + BOFF_FC1B + 16 * t + 4 * gq);
#pragma unroll
        for (int s = 0; s < 4; ++s)
#pragma unroll
            for (int t = 0; t < 8; ++t)
                acc3[t] = MFMA16(Wfc1b[(t * 4 + s) * 64 + lane], h2f[s], acc3[t]);
#pragma unroll
        for (int s = 0; s < 4; ++s) h3f[s] = packrelu(acc3, s);
    }

    // LSTM-state inputs: needed 2 layers from here; issue now
    bf16x8 h0f  = ld8f(h0 + row * 32 + 8 * gq);
    f32x4  c0r0 = *(const f32x4*)(c0 + row * 32 + 4 * gq);
    f32x4  c0r1 = *(const f32x4*)(c0 + row * 32 + 16 + 4 * gq);

    // ---- L1c: [h3, w_game] -> h4[64]  (w_game folded into bias) ----------
    bf16x8 h4f[2];
    {
        f32x4 acc4[4];
#pragma unroll
        for (int t = 0; t < 4; ++t)
            acc4[t] = *(const f32x4*)(wsb + BOFF_FC1C + 16 * t + 4 * gq);
#pragma unroll
        for (int s = 0; s < 4; ++s)
#pragma unroll
            for (int t = 0; t < 4; ++t)
                acc4[t] = MFMA16(Wfc1c[(t * 4 + s) * 64 + lane], h3f[s], acc4[t]);
#pragma unroll
        for (int s = 0; s < 2; ++s) h4f[s] = packrelu(acc4, s);
    }

    // ---- L2: h4[64] -> h5[32] --------------------------------------------
    bf16x8 h5f;
    {
        f32x4 acc5[2];
#pragma unroll
        for (int t = 0; t < 2; ++t)
            acc5[t] = *(const f32x4*)(wsb + BOFF_FC2 + 16 * t + 4 * gq);
#pragma unroll
        for (int s = 0; s < 2; ++s)
#pragma unroll
            for (int t = 0; t < 2; ++t)
                acc5[t] = MFMA16(Wfc2[(t * 2 + s) * 64 + lane], h4f[s], acc5[t]);
        h5f = packrelu(acc5, 0);
    }

    // ---- L3: h5[32] -> h6[32] --------------------------------------------
    bf16x8 h6f;
    {
        f32x4 acc6[2];
#pragma unroll
        for (int t = 0; t < 2; ++t)
            acc6[t] = *(const f32x4*)(wsb + BOFF_FC3 + 16 * t + 4 * gq);
#pragma unroll
        for (int t = 0; t < 2; ++t)
            acc6[t] = MFMA16(Wfc3[t * 64 + lane], h5f, acc6[t]);
        h6f = packrelu(acc6, 0);
    }

    // ---- LSTM gates ------------------------------------------------------
    bf16x8 hnf;
    {
        f32x4 accg[8];
#pragma unroll
        for (int t = 0; t < 8; ++t)
            accg[t] = *(const f32x4*)(wsb + BOFF_LSTM + 16 * t + 4 * gq);
#pragma unroll
        for (int t = 0; t < 8; ++t)
            accg[t] = MFMA16(Wwih[t * 64 + lane], h6f, accg[t]);
#pragma unroll
        for (int t = 0; t < 8; ++t)
            accg[t] = MFMA16(Wwhh[t * 64 + lane], h0f, accg[t]);
        // gate tiles: i -> {0,1}, f -> {2,3}, g -> {4,5}, o -> {6,7}
#pragma unroll
        for (int t2 = 0; t2 < 2; ++t2) {
            f32x4 cc = t2 ? c0r1 : c0r0;
#pragma unroll
            for (int r = 0; r < 4; ++r) {
                float ig = accg[t2][r];
                float fg = accg[2 + t2][r];
                float gg = accg[4 + t2][r];
                float og = accg[6 + t2][r];
                float cn = sigm(fg) * cc[r] + sigm(ig) * tanh_(gg);
                hnf[t2 * 4 + r] = (__bf16)(sigm(og) * tanh_(cn));
            }
        }
    }

    // ---- L4: h_new[32] -> o1[32] -----------------------------------------
    f32x4 acco[2];
#pragma unroll
    for (int t = 0; t < 2; ++t)
        acco[t] = *(const f32x4*)(wsb + BOFF_FC4 + 16 * t + 4 * gq);
#pragma unroll
    for (int t = 0; t < 2; ++t)
        acco[t] = MFMA16(Wfc4[t * 64 + lane], hnf, acco[t]);

    // ---- L5 + sigmoid ----------------------------------------------------
    f32x4 w5a = *(const f32x4*)(fc5w + 4 * gq);
    f32x4 w5b = *(const f32x4*)(fc5w + 16 + 4 * gq);
    float p = 0.f;
#pragma unroll
    for (int r = 0; r < 4; ++r) {
        p += fmaxf(acco[0][r], 0.f) * w5a[r];
        p += fmaxf(acco[1][r], 0.f) * w5b[r];
    }
    p += __shfl_xor(p, 16);
    p += __shfl_xor(p, 32);
    float res = sigm(p + fc5b[0]);
    if (lane < 16) out[rowbase + lane] = res;
}

// ---------------------------------------------------------------------------
extern "C" void kernel_launch(void* const* d_in, const int* in_sizes, int n_in,
                              void* d_out, int out_size, void* d_ws, size_t ws_size,
                              hipStream_t stream) {
    const float* x     = (const float*)d_in[0];
    const float* w     = (const float*)d_in[1];
    const float* h0    = (const float*)d_in[2];
    const float* c0    = (const float*)d_in[3];
    const float* fc1w  = (const float*)d_in[4];
    const float* fc1b  = (const float*)d_in[5];
    const float* fc1aw = (const float*)d_in[6];
    const float* fc1ab = (const float*)d_in[7];
    const float* fc1bw = (const float*)d_in[8];
    const float* fc1bb = (const float*)d_in[9];
    const float* wgame = (const float*)d_in[10];
    const float* fc1cw = (const float*)d_in[11];
    const float* fc1cb = (const float*)d_in[12];
    const float* fc2w  = (const float*)d_in[13];
    const float* fc2b  = (const float*)d_in[14];
    const float* fc3w  = (const float*)d_in[15];
    const float* fc3b  = (const float*)d_in[16];
    const float* wih   = (const float*)d_in[17];
    const float* whh   = (const float*)d_in[18];
    const float* bih   = (const float*)d_in[19];
    const float* bhh   = (const float*)d_in[20];
    const float* fc4w  = (const float*)d_in[21];
    const float* fc4b  = (const float*)d_in[22];
    const float* fc5w  = (const float*)d_in[23];
    const float* fc5b  = (const float*)d_in[24];

    __bf16* wsw = (__bf16*)d_ws;
    float*  wsb = (float*)((char*)d_ws + WTOT * sizeof(__bf16));
    (void)ws_size; (void)n_in; (void)out_size;

    const int Btot = in_sizes[0] / 256;   // 131072 rows

    prep_kernel<<<(WTOT + BTOT + 255) / 256, 256, 0, stream>>>(
        fc1w, fc1b, fc1aw, fc1ab, fc1bw, fc1bb, wgame, fc1cw, fc1cb,
        fc2w, fc2b, fc3w, fc3b, wih, whh, bih, bhh, fc4w, fc4b, wsw, wsb);

    fused_mlp_lstm<<<Btot / 256, 1024, 0, stream>>>(
        x, w, h0, c0, fc5w, fc5b, wsw, wsb, (float*)d_out);
}